// Round 2
// baseline (313.417 us; speedup 1.0000x reference)
//
#include <hip/hip_runtime.h>

#define BLK 256
#define DD  48
#define G   2                        // elements per thread, chains interleaved
#define INV2PI 0.15915494309189535f  // v_sin/v_cos take revolutions

// rho = a0*I + v.sigma (a0, v complex). Conjugation by U_k = Rz(-p1k)Ry(p0k)Rz(-p2k)
// leaves a0 invariant and rotates v. Adjacent Rz's across blocks merge:
//   Z(-p2_0), then for k=0..14: Y(p0_k), Z(-(p1_k + p2_{k+1})), then Y(p0_15), Z(-p1_15)
// => 33 rotations / 33 native sincos instead of 48.
//
// R7 change vs R6: drop LDS (R6 proved coalescing was not the bottleneck: the
// wave's 12KB strided footprint lives in L1). Instead: 2 elements per thread
// with the two rotation chains INTERLEAVED -> 2x in-flight VMEM bytes per
// wave, 2-way ILP on the serial trig/FMA dependency chain, half the
// load-burst/compute-idle phase alternation per delivered element.
__global__ __launch_bounds__(BLK) void qlayer_kernel(
    const float* __restrict__ rho_real,
    const float* __restrict__ rho_imag,
    const float* __restrict__ x,
    const float* __restrict__ w,
    const float* __restrict__ theta,
    float* __restrict__ out,
    long long n,            // number of elements B
    long long out_floats)   // d_out capacity in floats (4*n: REAL part only)
{
    const long long base = (long long)blockIdx.x * (G * BLK);
    const int tid = threadIdx.x;

    long long b[G];
    bool ok[G];
    #pragma unroll
    for (int u = 0; u < G; ++u) {
        b[u]  = base + u * BLK + tid;   // wave-contiguous for both elements
        ok[u] = b[u] < n;
    }

    // --- Load both x rows (12 float4 each) + both rho pairs, all issued
    //     up front so the full 2x footprint is in flight together. ---
    float xs[G][DD];
    float4 rr[G], ri[G];
    #pragma unroll
    for (int u = 0; u < G; ++u) {
        const float4* __restrict__ xv = reinterpret_cast<const float4*>(x + b[u] * DD);
        #pragma unroll
        for (int q = 0; q < 12; ++q) {
            float4 v = ok[u] ? xv[q] : make_float4(0.f, 0.f, 0.f, 0.f);
            xs[u][4 * q + 0] = v.x; xs[u][4 * q + 1] = v.y;
            xs[u][4 * q + 2] = v.z; xs[u][4 * q + 3] = v.w;
        }
        rr[u] = ok[u] ? reinterpret_cast<const float4*>(rho_real)[b[u]]
                      : make_float4(0.f, 0.f, 0.f, 0.f);
        ri[u] = ok[u] ? reinterpret_cast<const float4*>(rho_imag)[b[u]]
                      : make_float4(0.f, 0.f, 0.f, 0.f);
    }

    // --- Bloch decomposition (x2) ---
    float a0r[G], v1r[G], v1i[G], v2r[G], v2i[G], v3r[G], v3i[G];
    #pragma unroll
    for (int u = 0; u < G; ++u) {
        a0r[u] = 0.5f * (rr[u].x + rr[u].w);
        v1r[u] = 0.5f * (rr[u].y + rr[u].z); v1i[u] = 0.5f * (ri[u].y + ri[u].z);
        v2r[u] = 0.5f * (ri[u].z - ri[u].y); v2i[u] = 0.5f * (rr[u].y - rr[u].z);
        v3r[u] = 0.5f * (rr[u].x - rr[u].w); v3i[u] = 0.5f * (ri[u].x - ri[u].w);
    }

    // Plane-rotation helpers (native HW trig). Angle semantics match the
    // verified R5 kernel: rotZ(a) == Rz(-a) on (v1,v2); rotY(a) == Ry(a) on (v1,v3).
    // u is always a compile-time constant at the call site (unrolled loops),
    // so all array indexing SROAs to registers.
    auto rotZ = [&](int u, float ang) {
        float s = __builtin_amdgcn_sinf(ang * INV2PI);
        float c = __builtin_amdgcn_cosf(ang * INV2PI);
        float t1r = fmaf(c, v1r[u],  s * v2r[u]);
        float t1i = fmaf(c, v1i[u],  s * v2i[u]);
        v2r[u] = fmaf(c, v2r[u], -s * v1r[u]);
        v2i[u] = fmaf(c, v2i[u], -s * v1i[u]);
        v1r[u] = t1r; v1i[u] = t1i;
    };
    auto rotY = [&](int u, float ang) {
        float s = __builtin_amdgcn_sinf(ang * INV2PI);
        float c = __builtin_amdgcn_cosf(ang * INV2PI);
        float t1r = fmaf(c, v1r[u],  s * v3r[u]);
        float t1i = fmaf(c, v1i[u],  s * v3i[u]);
        v3r[u] = fmaf(c, v3r[u], -s * v1r[u]);
        v3i[u] = fmaf(c, v3i[u], -s * v1i[u]);
        v1r[u] = t1r; v1i[u] = t1i;
    };

    // --- Merged rotation chain, both elements interleaved per step ---
    #pragma unroll
    for (int u = 0; u < G; ++u)
        rotZ(u, fmaf(xs[u][2], w[2], theta[2]));             // Z(-p2_0)
    #pragma unroll
    for (int k = 0; k < 15; ++k) {
        const int j = 3 * k;
        #pragma unroll
        for (int u = 0; u < G; ++u)
            rotY(u, fmaf(xs[u][j], w[j], theta[j]));         // Y(p0_k)
        // Z(-(p1_k + p2_{k+1})): theta-sum is scalar math (compile-time idx)
        float ts = theta[j + 1] + theta[j + 5];
        #pragma unroll
        for (int u = 0; u < G; ++u)
            rotZ(u, fmaf(xs[u][j + 1], w[j + 1],
                         fmaf(xs[u][j + 5], w[j + 5], ts)));
    }
    #pragma unroll
    for (int u = 0; u < G; ++u) {
        rotY(u, fmaf(xs[u][45], w[45], theta[45]));          // Y(p0_15)
        rotZ(u, fmaf(xs[u][46], w[46], theta[46]));          // Z(-p1_15)
    }

    // --- Reassemble REAL parts only, store both elements ---
    #pragma unroll
    for (int u = 0; u < G; ++u) {
        if (!ok[u]) continue;
        float o0 = a0r[u] + v3r[u];
        float o1 = v1r[u] + v2i[u];
        float o2 = v1r[u] - v2i[u];
        float o3 = a0r[u] - v3r[u];
        if (4 * b[u] + 4 <= out_floats) {
            reinterpret_cast<float4*>(out)[b[u]] = make_float4(o0, o1, o2, o3);
        } else {
            float vals[4] = {o0, o1, o2, o3};
            for (int j = 0; j < 4; ++j) {
                long long o = 4 * b[u] + j;
                if (o < out_floats) out[o] = vals[j];
            }
        }
    }
}

extern "C" void kernel_launch(void* const* d_in, const int* in_sizes, int n_in,
                              void* d_out, int out_size, void* d_ws, size_t ws_size,
                              hipStream_t stream) {
    const float* rho_real = (const float*)d_in[0];
    const float* rho_imag = (const float*)d_in[1];
    const float* x        = (const float*)d_in[2];
    const float* w        = (const float*)d_in[3];
    const float* theta    = (const float*)d_in[4];
    float* out = (float*)d_out;

    long long nB = (long long)in_sizes[0] / 4;
    long long nX = (long long)in_sizes[2] / DD;
    long long n  = nB < nX ? nB : nX;
    if (n <= 0) return;

    long long per_block = (long long)G * BLK;
    int grid = (int)((n + per_block - 1) / per_block);
    qlayer_kernel<<<dim3(grid), dim3(BLK), 0, stream>>>(
        rho_real, rho_imag, x, w, theta, out, n, (long long)out_size);
}